// Round 16
// baseline (219.746 us; speedup 1.0000x reference)
//
#include <hip/hip_runtime.h>
#include <hip/hip_bf16.h>

#define N_NODES 50000
#define N_EDGES 800000
#define ET_EDGES 850000   // + self loops
#define HEADS 4
#define ENC_BLOCKS 1563   // ceil(N_NODES/32)

// bucketed CSR build
#define BSHIFT 8
#define NBUK 196          // ceil(50000/256)
#define BCAP 6144         // max edges/bucket
#define EB_PER_BLOCK 4096
#define EB_BLOCKS 208     // 208*4096 >= 850000

// fused GEMM grid: 64 nodes/block, 512 threads (8 waves)
#define G12NB 782
// aggregate1: 32 nodes/block (8-lane groups); aggdec2: 16 nodes/block (16-lane groups)
#define NAGG8_BLOCKS 1563 // ceil(50000/32)
#define NAGG_BLOCKS 3125  // 50000/16 exact

// packed weight table offsets (ushort units) inside wtb
#define W1HI 0            // [4][64][64]  w1t[h][q][k] = g1w[k*256+h*64+q]
#define W1LO 16384
#define W2HI 32768        // [64][256]    w2t[c][K]    = g2w[K*64+c]
#define W2LO 49152
#define GCHI 65536        // [16][256]    gc[j][K] = sum_cc g2w[K][h*16+cc]*(as|ad)[h*16+cc]
#define GCLO 69632
#define WT_TOTAL 73728

typedef __attribute__((ext_vector_type(8))) short bf16x8;
typedef __attribute__((ext_vector_type(4))) float f32x4;
#define MFMA16(a, b, c) __builtin_amdgcn_mfma_f32_16x16x32_bf16((a), (b), (c), 0, 0, 0)

__device__ __forceinline__ float lrelu(float v) { return v > 0.f ? v : 0.2f * v; }

// bf16 round-to-nearest-even pack/unpack
__device__ __forceinline__ unsigned short f2bf(float f) {
    unsigned int u = __float_as_uint(f);
    u = (u + 0x7FFFu + ((u >> 16) & 1u)) >> 16;
    return (unsigned short)u;
}
__device__ __forceinline__ float bf2f(unsigned short h) {
    return __uint_as_float((unsigned int)h << 16);
}

__device__ __forceinline__ void edge_sd(const int* __restrict__ ei, int e, int& s, int& d) {
    if (e < N_EDGES) { s = ei[e]; d = ei[N_EDGES + e]; }
    else { s = d = e - N_EDGES; }
}

// 8-feat bf16 row fragment x 4-head alpha accumulate
__device__ __forceinline__ void acc8(const bf16x8 r, const float4 pp, float (&acc)[8][4]) {
    #pragma unroll
    for (int f = 0; f < 8; ++f) {
        float v = bf2f((unsigned short)r[f]);
        acc[f][0] += v * pp.x; acc[f][1] += v * pp.y;
        acc[f][2] += v * pp.z; acc[f][3] += v * pp.w;
    }
}

// ---------------- zero bucket cursors + fold attention vectors + MFMA weight prep ----------------
__global__ __launch_bounds__(256) void zerofold_kernel(
    int* __restrict__ bcur,
    const float* __restrict__ g1w, const float* __restrict__ g1as, const float* __restrict__ g1ad,
    float* __restrict__ wsf, float* __restrict__ wdf,
    const float* __restrict__ g2w, const float* __restrict__ g2as, const float* __restrict__ g2ad,
    unsigned short* __restrict__ wtb) {
    int b = blockIdx.x;
    int tid = threadIdx.x;
    if (b == 0) {
        if (tid < NBUK) bcur[tid] = 0;
        return;
    }
    if (b == 1) {
        int h = tid >> 6, k = tid & 63;
        float as_acc = 0.f, ad_acc = 0.f;
        #pragma unroll 8
        for (int c = 0; c < 64; ++c) {
            float w = g1w[k * 256 + h * 64 + c];
            as_acc += w * g1as[h * 64 + c];
            ad_acc += w * g1ad[h * 64 + c];
        }
        wsf[tid] = as_acc;
        wdf[tid] = ad_acc;
        return;
    }
    if (b < 18) {
        int gidx0 = (b - 2) * 2048 + tid * 8;
        #pragma unroll
        for (int u = 0; u < 8; ++u) {
            int idx = gidx0 + u;            // 0..32767
            float w;
            int dst;
            if (idx < 16384) {              // w1t: idx = h*4096 + q*64 + k
                int h = idx >> 12, q = (idx >> 6) & 63, k = idx & 63;
                w = g1w[k * 256 + h * 64 + q];
                dst = W1HI + idx;
            } else {                        // w2t: i2 = c*256 + K
                int i2 = idx - 16384;
                int c = i2 >> 8, K = i2 & 255;
                w = g2w[K * 64 + c];
                dst = W2HI + i2;
            }
            unsigned short hi = f2bf(w);
            unsigned short lo = f2bf(w - bf2f(hi));
            wtb[dst] = hi;
            wtb[dst + 16384] = lo;
        }
        return;
    }
    // blocks 18..19: gc[j][K]
    {
        int gidx0 = (b - 18) * 2048 + tid * 8;
        #pragma unroll
        for (int u = 0; u < 8; ++u) {
            int idx = gidx0 + u;            // j*256 + K, j = 0..15
            int j = idx >> 8, K = idx & 255;
            float acc = 0.f;
            if (j < 8) {
                int h = j >> 1;
                const float* gv = (j & 1) ? g2ad : g2as;
                #pragma unroll
                for (int cc = 0; cc < 16; ++cc)
                    acc += g2w[K * 64 + h * 16 + cc] * gv[h * 16 + cc];
            }
            unsigned short hi = f2bf(acc);
            unsigned short lo = f2bf(acc - bf2f(hi));
            wtb[GCHI + idx] = hi;
            wtb[GCLO + idx] = lo;
        }
        return;
    }
}

// ---------------- mega: bucket-scatter edges (blocks 0..EB) + encoder/alpha1 (rest) ----------------
__global__ __launch_bounds__(256) void mega_kernel(
    const int* __restrict__ ei, int* __restrict__ bcur, int* __restrict__ ebuf,
    const float* __restrict__ x, const float* __restrict__ w1, const float* __restrict__ b1,
    const float* __restrict__ w2, const float* __restrict__ b2,
    const float* __restrict__ wsf, const float* __restrict__ wdf,
    unsigned short* __restrict__ henc, float* __restrict__ as1, float* __restrict__ ad1) {
    __shared__ union {
        struct { int es[EB_PER_BLOCK]; int ed[EB_PER_BLOCK]; int h[NBUK]; int base[NBUK]; } buk;
        struct { float w2[4096]; float t[32][64]; float xx[32][8]; float he[32][65]; float wf[8 * 65]; } enc;
    } u;
    int tid = threadIdx.x;
    if (blockIdx.x < EB_BLOCKS) {
        for (int i = tid; i < NBUK; i += 256) u.buk.h[i] = 0;
        int e0 = blockIdx.x * EB_PER_BLOCK;
        __syncthreads();
        #pragma unroll
        for (int r = 0; r < EB_PER_BLOCK / 256; ++r) {
            int i = r * 256 + tid;
            int e = e0 + i;
            if (e < ET_EDGES) {
                int s, d; edge_sd(ei, e, s, d);
                u.buk.es[i] = s;
                u.buk.ed[i] = d;
                atomicAdd(&u.buk.h[d >> BSHIFT], 1);
            } else {
                u.buk.ed[i] = -1;
            }
        }
        __syncthreads();
        for (int i = tid; i < NBUK; i += 256) {
            int c = u.buk.h[i];
            u.buk.base[i] = c ? atomicAdd(bcur + i, c) : 0;
            u.buk.h[i] = 0;   // reuse as cursor
        }
        __syncthreads();
        #pragma unroll
        for (int r = 0; r < EB_PER_BLOCK / 256; ++r) {
            int i = r * 256 + tid;
            int d = u.buk.ed[i];
            if (d >= 0) {
                int b = d >> BSHIFT;
                int off = atomicAdd(&u.buk.h[b], 1);
                ebuf[b * BCAP + u.buk.base[b] + off] = ((d & 255) << 16) | u.buk.es[i];
            }
        }
        return;
    }
    // ---- encoder + fused alpha1 (32 nodes/block) ----
    int node0 = (blockIdx.x - EB_BLOCKS) * 32;
    for (int i = tid; i < 4096; i += 256) u.enc.w2[i] = w2[i];
    for (int i = tid; i < 224; i += 256) {
        int src = node0 * 7 + i;
        u.enc.xx[i / 7][i % 7] = (src < N_NODES * 7) ? x[src] : 0.f;
    }
    for (int i = tid; i < 512; i += 256) {
        int g = i >> 6, k = i & 63;
        int h = g & 3;
        u.enc.wf[g * 65 + k] = (g < 4) ? wsf[h * 64 + k] : wdf[h * 64 + k];
    }
    int c = tid & 63;
    int mg = tid >> 6;
    float w1c[7];
    #pragma unroll
    for (int k = 0; k < 7; ++k) w1c[k] = w1[k * 64 + c];
    float b1c = b1[c];
    __syncthreads();
    #pragma unroll
    for (int m = 0; m < 8; ++m) {
        int nn = mg * 8 + m;
        float a = b1c;
        #pragma unroll
        for (int k = 0; k < 7; ++k) a += u.enc.xx[nn][k] * w1c[k];
        u.enc.t[nn][c] = fmaxf(a, 0.f);
    }
    __syncthreads();
    float acc[8];
    float b2c = b2[c];
    #pragma unroll
    for (int m = 0; m < 8; ++m) acc[m] = b2c;
    #pragma unroll 4
    for (int k = 0; k < 64; ++k) {
        float w = u.enc.w2[k * 64 + c];
        #pragma unroll
        for (int m = 0; m < 8; ++m) acc[m] += u.enc.t[mg * 8 + m][k] * w;
    }
    #pragma unroll
    for (int m = 0; m < 8; ++m) {
        int nn = mg * 8 + m;
        int node = node0 + nn;
        u.enc.he[nn][c] = acc[m];
        if (node < N_NODES) henc[node * 64 + c] = f2bf(acc[m]);
    }
    __syncthreads();
    {
        int nn = tid >> 3, r = tid & 7;
        int node = node0 + nn;
        const float* wf = u.enc.wf + r * 65;
        float sum = 0.f;
        #pragma unroll 8
        for (int k = 0; k < 64; ++k) sum += u.enc.he[nn][k] * wf[k];
        if (node < N_NODES) {
            int hh = r & 3;
            if (r < 4) as1[node * 4 + hh] = sum;
            else       ad1[node * 4 + hh] = sum;
        }
    }
}

// ---------------- per-bucket CSR finalize: 1 block = 256-node bucket ----------------
__global__ __launch_bounds__(256) void bucket_csr_kernel(
    const int* __restrict__ ebuf, const int* __restrict__ bcur,
    int* __restrict__ rowbeg, int* __restrict__ degarr, int* __restrict__ csr_src) {
    __shared__ int s_deg[256];
    __shared__ int s_cur[256];
    __shared__ int s_w[4];
    int b = blockIdx.x;
    int tid = threadIdx.x;
    s_deg[tid] = 0;
    int cnt = bcur[b];
    int base = b * BCAP;
    const int* eb = ebuf + base;
    int node0 = b << BSHIFT;
    __syncthreads();
    for (int i = tid; i < cnt; i += 256) atomicAdd(&s_deg[eb[i] >> 16], 1);
    __syncthreads();
    int v = s_deg[tid];
    int lane = tid & 63, w = tid >> 6;
    int xv = v;
    #pragma unroll
    for (int off = 1; off < 64; off <<= 1) {
        int t = __shfl_up(xv, off);
        if (lane >= off) xv += t;
    }
    if (lane == 63) s_w[w] = xv;
    __syncthreads();
    if (tid == 0) {
        int a = 0;
        #pragma unroll
        for (int j = 0; j < 4; ++j) { int t = s_w[j]; s_w[j] = a; a += t; }
    }
    __syncthreads();
    int excl = xv - v + s_w[w];
    s_cur[tid] = excl;
    int node = node0 + tid;
    if (node < N_NODES) {
        rowbeg[node] = base + excl;
        degarr[node] = v;
    }
    __syncthreads();
    for (int i = tid; i < cnt; i += 256) {
        int p = eb[i];
        int pos = atomicAdd(&s_cur[p >> 16], 1);
        csr_src[base + pos] = p & 0xFFFF;
    }
}

// ---------------- GAT1 aggregate: 1 node per 8-lane group, 16B feature loads ----------------
__global__ __launch_bounds__(256) void aggregate1_kernel(
    const int* __restrict__ rowbeg, const int* __restrict__ degarr, const int* __restrict__ csr_src,
    const float* __restrict__ as, const float* __restrict__ ad,
    const unsigned short* __restrict__ henc, unsigned short* __restrict__ agg) {
    __shared__ int    ls[32][9];
    __shared__ float4 lp[32][9];
    int tid = threadIdx.x;
    int gg = tid >> 3, lane8 = tid & 7;
    int n = blockIdx.x * 32 + gg;
    if (n >= N_NODES) return;
    int base = rowbeg[n];
    int deg  = degarr[n];
    float4 add = *(const float4*)(ad + n * 4);

    float4 l = make_float4(0.f, 0.f, 0.f, 0.f);
    float acc[8][4];   // [feat][head], feats lane8*8..+7
    #pragma unroll
    for (int f = 0; f < 8; ++f)
        #pragma unroll
        for (int h = 0; h < 4; ++h) acc[f][h] = 0.f;

    for (int c0 = 0; c0 < deg; c0 += 8) {
        int j = c0 + lane8;
        int s = 0;
        float4 p = make_float4(0.f, 0.f, 0.f, 0.f);
        if (j < deg) {
            s = csr_src[base + j];
            float4 a = *(const float4*)(as + s * 4);
            p.x = __expf(lrelu(a.x + add.x));
            p.y = __expf(lrelu(a.y + add.y));
            p.z = __expf(lrelu(a.z + add.z));
            p.w = __expf(lrelu(a.w + add.w));
            l.x += p.x; l.y += p.y; l.z += p.z; l.w += p.w;
        }
        ls[gg][lane8] = s;
        lp[gg][lane8] = p;
        int cnt = min(8, deg - c0);
        const int*    lsw = ls[gg];
        const float4* lpw = lp[gg];
        int e = 0;
        for (; e + 4 <= cnt; e += 4) {
            bf16x8 r0 = *(const bf16x8*)(henc + lsw[e+0] * 64 + lane8 * 8);
            bf16x8 r1 = *(const bf16x8*)(henc + lsw[e+1] * 64 + lane8 * 8);
            bf16x8 r2 = *(const bf16x8*)(henc + lsw[e+2] * 64 + lane8 * 8);
            bf16x8 r3 = *(const bf16x8*)(henc + lsw[e+3] * 64 + lane8 * 8);
            float4 p0 = lpw[e+0], p1 = lpw[e+1], p2 = lpw[e+2], p3 = lpw[e+3];
            acc8(r0, p0, acc); acc8(r1, p1, acc);
            acc8(r2, p2, acc); acc8(r3, p3, acc);
        }
        for (; e < cnt; ++e) {
            bf16x8 r = *(const bf16x8*)(henc + lsw[e] * 64 + lane8 * 8);
            acc8(r, lpw[e], acc);
        }
    }
    // denominator reduce across the 8-lane group
    #pragma unroll
    for (int off = 1; off < 8; off <<= 1) {
        l.x += __shfl_xor(l.x, off);
        l.y += __shfl_xor(l.y, off);
        l.z += __shfl_xor(l.z, off);
        l.w += __shfl_xor(l.w, off);
    }
    float inv[4];
    inv[0] = 1.f / (l.x + 1e-16f);
    inv[1] = 1.f / (l.y + 1e-16f);
    inv[2] = 1.f / (l.z + 1e-16f);
    inv[3] = 1.f / (l.w + 1e-16f);
    const size_t PL = (size_t)N_NODES * 64;
    #pragma unroll
    for (int h = 0; h < 4; ++h) {
        bf16x8 o;
        #pragma unroll
        for (int f = 0; f < 8; ++f) o[f] = (short)f2bf(acc[f][h] * inv[h]);
        *(bf16x8*)(agg + h * PL + (size_t)n * 64 + lane8 * 8) = o;
    }
}

// ---------------- fused GEMM1+GEMM2 (MFMA): 64 nodes/block, 8 waves, hi-only weights ----------------
// bf16-hi weights only; LDS 72KB + VGPR<=128 (launch_bounds 4 waves/EU) -> 2 blocks/CU.
// phase A: wave w -> rows [(w&3)*16,+16), heads {2*(w>>2),+1}
// phase C: rows same, cols [(w>>2)*32,+32); gc on waves w<4. Row-XOR swizzle byte ^= (row&7)<<4.
__global__ __launch_bounds__(512, 4) void gemm12_kernel(
    const unsigned short* __restrict__ agg, const unsigned short* __restrict__ wtb,
    const float* __restrict__ g1b, unsigned short* __restrict__ h2,
    float* __restrict__ as2, float* __restrict__ ad2) {
    __shared__ unsigned short sw[20480];   // 40KB: phase A = W1 hi; phase C = W2 hi + gc hi
    __shared__ unsigned short s1[16384];   // 32KB out1 tile [64][256], row-xor swizzled
    int tid = threadIdx.x;
    int node0 = blockIdx.x * 64;
    int lane = tid & 63, w = tid >> 6;
    int lrow = lane & 15, g = lane >> 4;
    int rw = w & 3, hp = w >> 2;           // row-tile / head-pair (phase A) = col-half (phase C)
    const size_t PL = (size_t)N_NODES * 64;

    // stage W1 hi (32KB, 2048 uint4): row stride 128B = 8 uint4 -> xor (i>>3)&7
    {
        const uint4* src = (const uint4*)(wtb + W1HI);
        uint4* dst = (uint4*)sw;
        #pragma unroll
        for (int r = 0; r < 4; ++r) {
            int i = r * 512 + tid;
            dst[i ^ ((i >> 3) & 7)] = src[i];
        }
    }
    // A-fragments + biases (latency hides under staging)
    int arow = node0 + rw * 16 + lrow;
    if (arow >= N_NODES) arow = N_NODES - 1;   // clamp; garbage rows masked at final store
    bf16x8 aF[2][2];
    #pragma unroll
    for (int hh = 0; hh < 2; ++hh)
        #pragma unroll
        for (int ks = 0; ks < 2; ++ks)
            aF[hh][ks] = *(const bf16x8*)(agg + (size_t)(hp * 2 + hh) * PL + (size_t)arow * 64 + ks * 32 + g * 8);
    float bb[2][4];
    #pragma unroll
    for (int hh = 0; hh < 2; ++hh)
        #pragma unroll
        for (int qt = 0; qt < 4; ++qt)
            bb[hh][qt] = g1b[(hp * 2 + hh) * 64 + qt * 16 + lrow];
    __syncthreads();

    // ---- phase A: gemm1, 2 heads, rows [rw*16,+16) ----
    f32x4 acc1[2][4];
    #pragma unroll
    for (int hh = 0; hh < 2; ++hh)
        #pragma unroll
        for (int qt = 0; qt < 4; ++qt) acc1[hh][qt] = (f32x4){0.f, 0.f, 0.f, 0.f};
    #pragma unroll
    for (int hh = 0; hh < 2; ++hh) {
        int h = hp * 2 + hh;
        #pragma unroll
        for (int ks = 0; ks < 2; ++ks) {
            #pragma unroll
            for (int qt = 0; qt < 4; ++qt) {
                int q = qt * 16 + lrow;
                int byt = (h * 8192 + q * 128 + ks * 64 + g * 16) ^ ((q & 7) << 4);
                bf16x8 bH = *(const bf16x8*)((char*)sw + byt);
                acc1[hh][qt] = MFMA16(aF[hh][ks], bH, acc1[hh][qt]);
            }
        }
    }
    // epilogue A: bias + ELU -> s1 (swizzled). D layout: col = lrow, row = g*4+i.
    #pragma unroll
    for (int hh = 0; hh < 2; ++hh) {
        int h = hp * 2 + hh;
        #pragma unroll
        for (int qt = 0; qt < 4; ++qt) {
            int col = h * 64 + qt * 16 + lrow;
            #pragma unroll
            for (int i = 0; i < 4; ++i) {
                int r = rw * 16 + g * 4 + i;
                float t = acc1[hh][qt][i] + bb[hh][qt];
                t = t > 0.f ? t : (__expf(t) - 1.f);
                int byt = (r * 512 + col * 2) ^ ((r & 7) << 4);
                *(unsigned short*)((char*)s1 + byt) = f2bf(t);
            }
        }
    }
    __syncthreads();
    // stage W2 hi (32KB, 2048 uint4) + gc hi (8KB, 512 uint4) global->LDS:
    // row stride 512B = 32 uint4 -> xor (i>>5)&7 within each region
    {
        const uint4* srcw = (const uint4*)(wtb + W2HI);
        const uint4* srcg = (const uint4*)(wtb + GCHI);
        uint4* dst = (uint4*)sw;
        #pragma unroll
        for (int r = 0; r < 4; ++r) {
            int i = r * 512 + tid;
            dst[i ^ ((i >> 5) & 7)] = srcw[i];
        }
        {
            int i = tid;   // 0..511
            uint4* dst2 = dst + 2048;
            dst2[i ^ ((i >> 5) & 7)] = srcg[i];
        }
    }
    __syncthreads();
    // ---- phase C: gemm2 + gc, K=256 from s1; cols [hp*32,+32) ----
    f32x4 acc2[2];
    f32x4 accg = (f32x4){0.f, 0.f, 0.f, 0.f};
    acc2[0] = (f32x4){0.f, 0.f, 0.f, 0.f};
    acc2[1] = (f32x4){0.f, 0.f, 0.f, 0.f};
    int rloc = rw * 16 + lrow;
    int rx = (rloc & 7) << 4;
    #pragma unroll
    for (int ks = 0; ks < 8; ++ks) {
        int kb = ks * 64 + g * 16;
        bf16x8 aF2 = *(const bf16x8*)((char*)s1 + ((rloc * 512 + kb) ^ rx));
        #pragma unroll
        for (int qt = 0; qt < 2; ++qt) {
            int c = (hp * 2 + qt) * 16 + lrow;
            int byt = (c * 512 + kb) ^ ((c & 7) << 4);
            bf16x8 bH = *(const bf16x8*)((char*)sw + byt);
            acc2[qt] = MFMA16(aF2, bH, acc2[qt]);
        }
        if (hp == 0) {
            int byt = 32768 + ((lrow * 512 + kb) ^ ((lrow & 7) << 4));
            bf16x8 gH = *(const bf16x8*)((char*)sw + byt);
            accg = MFMA16(aF2, gH, accg);
        }
    }
    // epilogue C: h2 bf16 store + as2/ad2 (gc cols: even->as, odd->ad)
    #pragma unroll
    for (int i = 0; i < 4; ++i) {
        int node = node0 + rw * 16 + g * 4 + i;
        if (node < N_NODES) {
            #pragma unroll
            for (int qt = 0; qt < 2; ++qt)
                h2[(size_t)node * 64 + (hp * 2 + qt) * 16 + lrow] = f2bf(acc2[qt][i]);
            if (hp == 0 && lrow < 8) {
                float v = accg[i];
                int hh = lrow >> 1;
                if (lrow & 1) ad2[node * 4 + hh] = v;
                else          as2[node * 4 + hh] = v;
            }
        }
    }
}

// ---------------- GAT2 aggregate + fused decoder: 1 node per 16-lane group ----------------
// weight staging = 4 float4/thread (full 16KB w1) + w2; one barrier; decode is
// intra-16-lane-group (v in group-local LDS row, wave-synchronous, no block barrier)
__global__ __launch_bounds__(256) void aggdec2_kernel(
    const int* __restrict__ rowbeg, const int* __restrict__ degarr, const int* __restrict__ csr_src,
    const float* __restrict__ as, const float* __restrict__ ad,
    const unsigned short* __restrict__ h, const float* __restrict__ gb,
    const float* __restrict__ w1, const float* __restrict__ b1,
    const float* __restrict__ w2, const float* __restrict__ b2,
    float* __restrict__ out) {
    __shared__ int    ls[16][17];
    __shared__ float4 lp[16][17];
    __shared__ float  s_w1[4096];    // dec_w1 [k][c], 16KB
    __shared__ float  s_w2[256];     // dec_w2 [c][j], 1KB
    __shared__ float  s_v[16][68];   // per-group decoder input row
    int tid = threadIdx.x;
    // stage decoder weights: 4096 floats = 1024 float4 = 4 float4/thread (+64 threads for w2)
    #pragma unroll
    for (int r = 0; r < 4; ++r) {
        int i = r * 256 + tid;       // 0..1023 float4 index
        *(float4*)(s_w1 + i * 4) = *(const float4*)(w1 + i * 4);
    }
    if (tid < 64) *(float4*)(s_w2 + tid * 4) = *(const float4*)(w2 + tid * 4);
    __syncthreads();

    int gg = tid >> 4, lane16 = tid & 15;
    int n = blockIdx.x * 16 + gg;    // N_NODES = 3125*16 exactly -> always < N_NODES
    if (n >= N_NODES) return;
    int base = rowbeg[n];
    int deg  = degarr[n];
    int head = lane16 >> 2;          // 4 feats per lane, all in this head
    float4 add = *(const float4*)(ad + n * 4);

    float4 l = make_float4(0.f, 0.f, 0.f, 0.f);
    float acc[4];
    acc[0] = acc[1] = acc[2] = acc[3] = 0.f;

    for (int c0 = 0; c0 < deg; c0 += 16) {
        int j = c0 + lane16;
        int s = 0;
        float4 p = make_float4(0.f, 0.f, 0.f, 0.f);
        if (j < deg) {
            s = csr_src[base + j];
            float4 a = *(const float4*)(as + s * 4);
            p.x = __expf(lrelu(a.x + add.x));
            p.y = __expf(lrelu(a.y + add.y));
            p.z = __expf(lrelu(a.z + add.z));
            p.w = __expf(lrelu(a.w + add.w));
            l.x += p.x; l.y += p.y; l.z += p.z; l.w += p.w;
        }
        ls[gg][lane16] = s;
        lp[gg][lane16] = p;
        int cnt = min(16, deg - c0);
        const int*   lsw = ls[gg];
        const float* lpf = (const float*)lp[gg];
        int e = 0;
        for (; e + 4 <= cnt; e += 4) {
            ushort4 r0 = *(const ushort4*)(h + lsw[e+0] * 64 + lane16 * 4);
            ushort4 r1 = *(const ushort4*)(h + lsw[e+1] * 64 + lane16 * 4);
            ushort4 r2 = *(const ushort4*)(h + lsw[e+2] * 64 + lane16 * 4);
            ushort4 r3 = *(const ushort4*)(h + lsw[e+3] * 64 + lane16 * 4);
            float p0 = lpf[(e+0) * 4 + head];
            float p1 = lpf[(e+1) * 4 + head];
            float p2 = lpf[(e+2) * 4 + head];
            float p3 = lpf[(e+3) * 4 + head];
            acc[0] += bf2f(r0.x)*p0 + bf2f(r1.x)*p1 + bf2f(r2.x)*p2 + bf2f(r3.x)*p3;
            acc[1] += bf2f(r0.y)*p0 + bf2f(r1.y)*p1 + bf2f(r2.y)*p2 + bf2f(r3.y)*p3;
            acc[2] += bf2f(r0.z)*p0 + bf2f(r1.z)*p1 + bf2f(r2.z)*p2 + bf2f(r3.z)*p3;
            acc[3] += bf2f(r0.w)*p0 + bf2f(r1.w)*p1 + bf2f(r2.w)*p2 + bf2f(r3.w)*p3;
        }
        for (; e < cnt; ++e) {
            ushort4 r = *(const ushort4*)(h + lsw[e] * 64 + lane16 * 4);
            float pe = lpf[e * 4 + head];
            acc[0] += bf2f(r.x) * pe;
            acc[1] += bf2f(r.y) * pe;
            acc[2] += bf2f(r.z) * pe;
            acc[3] += bf2f(r.w) * pe;
        }
    }
    #pragma unroll
    for (int off = 1; off < 16; off <<= 1) {
        l.x += __shfl_xor(l.x, off);
        l.y += __shfl_xor(l.y, off);
        l.z += __shfl_xor(l.z, off);
        l.w += __shfl_xor(l.w, off);
    }
    float lh = (head == 0) ? l.x : (head == 1) ? l.y : (head == 2) ? l.z : l.w;
    float inv = 1.f / (lh + 1e-16f);
    // ---- fused decoder (intra-group; wave-synchronous LDS, no block barrier) ----
    int c0v = lane16 * 4;
    float4 vv;
    vv.x = acc[0] * inv + gb[c0v + 0];
    vv.y = acc[1] * inv + gb[c0v + 1];
    vv.z = acc[2] * inv + gb[c0v + 2];
    vv.w = acc[3] * inv + gb[c0v + 3];
    *(float4*)(&s_v[gg][c0v]) = vv;
    // layer 1: t[c] = relu(b1[c] + sum_k v[k]*w1[k][c]), c = c0v..c0v+3
    float t0 = b1[c0v + 0], t1 = b1[c0v + 1], t2 = b1[c0v + 2], t3 = b1[c0v + 3];
    #pragma unroll 8
    for (int k = 0; k < 64; ++k) {
        float vk = s_v[gg][k];
        float4 wv = *(const float4*)(s_w1 + k * 64 + c0v);
        t0 += vk * wv.x; t1 += vk * wv.y; t2 += vk * wv.z; t3 += vk * wv.w;
    }
    t0 = fmaxf(t0, 0.f); t1 = fmaxf(t1, 0.f); t2 = fmaxf(t2, 0.f); t3 = fmaxf(t3, 0.f);
    // layer 2: out[j] = b2[j] + sum_c t[c]*w2[c][j] (per-lane partial, 16-lane tree reduce)
    float4 w20 = *(const float4*)(s_w2 + (c0v + 0) * 4);
    float4 w21 = *(const float4*)(s_w2 + (c0v + 1) * 4);
    float4 w22 = *(const float4*)(s_w2 + (c0v + 2) * 4);
    float4 w23 = *(const float4*)(s_w2 + (c0v + 3) * 4);
    float o0 = t0 * w20.x + t1 * w21.x + t2 * w22.x + t3 * w23.x;
    float o1 = t0 * w20.y + t1 * w21.y + t2 * w22.y + t3 * w23.y;
    float o2 = t0 * w20.z + t1 * w21.z + t2 * w22.z + t3 * w23.z;
    float o3 = t0 * w20.w + t1 * w21.w + t2 * w22.w + t3 * w23.w;
    #pragma unroll
    for (int off = 1; off < 16; off <<= 1) {
        o0 += __shfl_xor(o0, off);
        o1 += __shfl_xor(o1, off);
        o2 += __shfl_xor(o2, off);
        o3 += __shfl_xor(o3, off);
    }
    if (lane16 == 0) {
        *(float4*)(out + (size_t)n * 4) =
            make_float4(o0 + b2[0], o1 + b2[1], o2 + b2[2], o3 + b2[3]);
    }
}

extern "C" void kernel_launch(void* const* d_in, const int* in_sizes, int n_in,
                              void* d_out, int out_size, void* d_ws, size_t ws_size,
                              hipStream_t stream) {
    const float* x      = (const float*)d_in[0];
    const int*   ei     = (const int*)d_in[1];
    const float* enc_w1 = (const float*)d_in[2];
    const float* enc_b1 = (const float*)d_in[3];
    const float* enc_w2 = (const float*)d_in[4];
    const float* enc_b2 = (const float*)d_in[5];
    const float* g1_w   = (const float*)d_in[6];
    const float* g1_as  = (const float*)d_in[7];
    const float* g1_ad  = (const float*)d_in[8];
    const float* g1_b   = (const float*)d_in[9];
    const float* g2_w   = (const float*)d_in[10];
    const float* g2_as  = (const float*)d_in[11];
    const float* g2_ad  = (const float*)d_in[12];
    const float* g2_b   = (const float*)d_in[13];
    const float* dec_w1 = (const float*)d_in[14];
    const float* dec_b1 = (const float*)d_in[15];
    const float* dec_w2 = (const float*)d_in[16];
    const float* dec_b2 = (const float*)d_in[17];

    const int N = N_NODES;

    // workspace layout (float offsets)
    float* ws   = (float*)d_ws;
    unsigned short* henc = (unsigned short*)ws;                   // 3.2M bf16 = [0,1.6M) floats
    unsigned short* wtb  = (unsigned short*)(ws + 1700000);       // 73728 bf16 weight table (dead gap)
    unsigned short* agg  = (unsigned short*)(ws + 3200000);       // 12.8M bf16 planar [h][n][k]
    unsigned short* h2   = (unsigned short*)(ws + 16000000);      // 3.2M bf16
    unsigned short* out1 = (unsigned short*)(ws + 22400000);      // (dead; ebuf alias only)
    float* as1  = ws + 35200000;
    float* ad1  = as1 + 200000;
    float* as2  = ad1 + 200000;
    float* ad2  = as2 + 200000;
    float* wsf  = ad2 + 200000;              // 256
    float* wdf  = wsf + 256;                 // 256
    int*   ebuf = (int*)out1;                // NBUK*BCAP ints = 4.8 MB
    int*   ib      = (int*)(ws + 36001024);
    int*   bcur    = ib;                     // 256
    int*   rowbeg  = ib + 256;               // 50,176
    int*   degarr  = ib + 50432;             // 50,176
    int*   csr_src = ib + 100608;            // NBUK*BCAP = 1,204,224

    // 1. zero bucket cursors + fold attention vectors + MFMA weight prep
    zerofold_kernel<<<20, 256, 0, stream>>>(bcur, g1_w, g1_as, g1_ad, wsf, wdf,
                                            g2_w, g2_as, g2_ad, wtb);
    // 2. bucket-scatter edges (packed int) + encoder/alpha1 (fused; henc bf16)
    mega_kernel<<<EB_BLOCKS + ENC_BLOCKS, 256, 0, stream>>>(
        ei, bcur, ebuf, x, enc_w1, enc_b1, enc_w2, enc_b2, wsf, wdf, henc, as1, ad1);
    // 3. per-bucket CSR finalize
    bucket_csr_kernel<<<NBUK, 256, 0, stream>>>(ebuf, bcur, rowbeg, degarr, csr_src);

    // 4. GAT1 aggregate (8-lane groups, 16B loads, bf16 planar out)
    aggregate1_kernel<<<NAGG8_BLOCKS, 256, 0, stream>>>(rowbeg, degarr, csr_src, as1, ad1, henc, agg);
    // 5. fused GEMM1+GEMM2 (MFMA, 8 waves, hi-only LDS weights, VGPR-capped for 2 blocks/CU)
    gemm12_kernel<<<G12NB, 512, 0, stream>>>(agg, wtb, g1_b, h2, as2, ad2);

    // 6. GAT2 aggregate + fused decoder (16-lane groups; writes d_out directly)
    aggdec2_kernel<<<NAGG_BLOCKS, 256, 0, stream>>>(rowbeg, degarr, csr_src, as2, ad2, h2,
                                                    g2_b, dec_w1, dec_b1, dec_w2, dec_b2,
                                                    (float*)d_out);
}

// Round 17
// 216.227 us; speedup vs baseline: 1.0163x; 1.0163x over previous
//
#include <hip/hip_runtime.h>
#include <hip/hip_bf16.h>

#define N_NODES 50000
#define N_EDGES 800000
#define ET_EDGES 850000   // + self loops
#define HEADS 4
#define ENC_BLOCKS 1563   // ceil(N_NODES/32)

// bucketed CSR build
#define BSHIFT 8
#define NBUK 196          // ceil(50000/256)
#define BCAP 6144         // max edges/bucket
#define EB_PER_BLOCK 4096
#define EB_BLOCKS 208     // 208*4096 >= 850000

// fused GEMM grid: 64 nodes/block, 512 threads (8 waves)
#define G12NB 782
// aggregate1: 32 nodes/block (8-lane groups); aggdec2: 16 nodes/block (16-lane groups)
#define NAGG8_BLOCKS 1563 // ceil(50000/32)
#define NAGG_BLOCKS 3125  // 50000/16 exact

// packed weight table offsets (ushort units) inside wtb
#define W1HI 0            // [4][64][64]  w1t[h][q][k] = g1w[k*256+h*64+q]
#define W1LO 16384
#define W2HI 32768        // [64][256]    w2t[c][K]    = g2w[K*64+c]
#define W2LO 49152
#define GCHI 65536        // [16][256]    gc[j][K] = sum_cc g2w[K][h*16+cc]*(as|ad)[h*16+cc]
#define GCLO 69632
#define WT_TOTAL 73728

typedef __attribute__((ext_vector_type(8))) short bf16x8;
typedef __attribute__((ext_vector_type(4))) float f32x4;
#define MFMA16(a, b, c) __builtin_amdgcn_mfma_f32_16x16x32_bf16((a), (b), (c), 0, 0, 0)

__device__ __forceinline__ float lrelu(float v) { return v > 0.f ? v : 0.2f * v; }

// bf16 round-to-nearest-even pack/unpack
__device__ __forceinline__ unsigned short f2bf(float f) {
    unsigned int u = __float_as_uint(f);
    u = (u + 0x7FFFu + ((u >> 16) & 1u)) >> 16;
    return (unsigned short)u;
}
__device__ __forceinline__ float bf2f(unsigned short h) {
    return __uint_as_float((unsigned int)h << 16);
}

__device__ __forceinline__ void edge_sd(const int* __restrict__ ei, int e, int& s, int& d) {
    if (e < N_EDGES) { s = ei[e]; d = ei[N_EDGES + e]; }
    else { s = d = e - N_EDGES; }
}

// 8-feat bf16 row fragment x 4-head alpha accumulate
__device__ __forceinline__ void acc8(const bf16x8 r, const float4 pp, float (&acc)[8][4]) {
    #pragma unroll
    for (int f = 0; f < 8; ++f) {
        float v = bf2f((unsigned short)r[f]);
        acc[f][0] += v * pp.x; acc[f][1] += v * pp.y;
        acc[f][2] += v * pp.z; acc[f][3] += v * pp.w;
    }
}

// ---------------- zero bucket cursors + fold attention vectors + MFMA weight prep ----------------
__global__ __launch_bounds__(256) void zerofold_kernel(
    int* __restrict__ bcur,
    const float* __restrict__ g1w, const float* __restrict__ g1as, const float* __restrict__ g1ad,
    float* __restrict__ wsf, float* __restrict__ wdf,
    const float* __restrict__ g2w, const float* __restrict__ g2as, const float* __restrict__ g2ad,
    unsigned short* __restrict__ wtb) {
    int b = blockIdx.x;
    int tid = threadIdx.x;
    if (b == 0) {
        if (tid < NBUK) bcur[tid] = 0;
        return;
    }
    if (b == 1) {
        int h = tid >> 6, k = tid & 63;
        float as_acc = 0.f, ad_acc = 0.f;
        #pragma unroll 8
        for (int c = 0; c < 64; ++c) {
            float w = g1w[k * 256 + h * 64 + c];
            as_acc += w * g1as[h * 64 + c];
            ad_acc += w * g1ad[h * 64 + c];
        }
        wsf[tid] = as_acc;
        wdf[tid] = ad_acc;
        return;
    }
    if (b < 18) {
        int gidx0 = (b - 2) * 2048 + tid * 8;
        #pragma unroll
        for (int u = 0; u < 8; ++u) {
            int idx = gidx0 + u;            // 0..32767
            float w;
            int dst;
            if (idx < 16384) {              // w1t: idx = h*4096 + q*64 + k
                int h = idx >> 12, q = (idx >> 6) & 63, k = idx & 63;
                w = g1w[k * 256 + h * 64 + q];
                dst = W1HI + idx;
            } else {                        // w2t: i2 = c*256 + K
                int i2 = idx - 16384;
                int c = i2 >> 8, K = i2 & 255;
                w = g2w[K * 64 + c];
                dst = W2HI + i2;
            }
            unsigned short hi = f2bf(w);
            unsigned short lo = f2bf(w - bf2f(hi));
            wtb[dst] = hi;
            wtb[dst + 16384] = lo;
        }
        return;
    }
    // blocks 18..19: gc[j][K]
    {
        int gidx0 = (b - 18) * 2048 + tid * 8;
        #pragma unroll
        for (int u = 0; u < 8; ++u) {
            int idx = gidx0 + u;            // j*256 + K, j = 0..15
            int j = idx >> 8, K = idx & 255;
            float acc = 0.f;
            if (j < 8) {
                int h = j >> 1;
                const float* gv = (j & 1) ? g2ad : g2as;
                #pragma unroll
                for (int cc = 0; cc < 16; ++cc)
                    acc += g2w[K * 64 + h * 16 + cc] * gv[h * 16 + cc];
            }
            unsigned short hi = f2bf(acc);
            unsigned short lo = f2bf(acc - bf2f(hi));
            wtb[GCHI + idx] = hi;
            wtb[GCLO + idx] = lo;
        }
        return;
    }
}

// ---------------- mega: bucket-scatter edges (blocks 0..EB) + encoder/alpha1 (rest) ----------------
__global__ __launch_bounds__(256) void mega_kernel(
    const int* __restrict__ ei, int* __restrict__ bcur, int* __restrict__ ebuf,
    const float* __restrict__ x, const float* __restrict__ w1, const float* __restrict__ b1,
    const float* __restrict__ w2, const float* __restrict__ b2,
    const float* __restrict__ wsf, const float* __restrict__ wdf,
    unsigned short* __restrict__ henc, float* __restrict__ as1, float* __restrict__ ad1) {
    __shared__ union {
        struct { int es[EB_PER_BLOCK]; int ed[EB_PER_BLOCK]; int h[NBUK]; int base[NBUK]; } buk;
        struct { float w2[4096]; float t[32][64]; float xx[32][8]; float he[32][65]; float wf[8 * 65]; } enc;
    } u;
    int tid = threadIdx.x;
    if (blockIdx.x < EB_BLOCKS) {
        for (int i = tid; i < NBUK; i += 256) u.buk.h[i] = 0;
        int e0 = blockIdx.x * EB_PER_BLOCK;
        __syncthreads();
        #pragma unroll
        for (int r = 0; r < EB_PER_BLOCK / 256; ++r) {
            int i = r * 256 + tid;
            int e = e0 + i;
            if (e < ET_EDGES) {
                int s, d; edge_sd(ei, e, s, d);
                u.buk.es[i] = s;
                u.buk.ed[i] = d;
                atomicAdd(&u.buk.h[d >> BSHIFT], 1);
            } else {
                u.buk.ed[i] = -1;
            }
        }
        __syncthreads();
        for (int i = tid; i < NBUK; i += 256) {
            int c = u.buk.h[i];
            u.buk.base[i] = c ? atomicAdd(bcur + i, c) : 0;
            u.buk.h[i] = 0;   // reuse as cursor
        }
        __syncthreads();
        #pragma unroll
        for (int r = 0; r < EB_PER_BLOCK / 256; ++r) {
            int i = r * 256 + tid;
            int d = u.buk.ed[i];
            if (d >= 0) {
                int b = d >> BSHIFT;
                int off = atomicAdd(&u.buk.h[b], 1);
                ebuf[b * BCAP + u.buk.base[b] + off] = ((d & 255) << 16) | u.buk.es[i];
            }
        }
        return;
    }
    // ---- encoder + fused alpha1 (32 nodes/block) ----
    int node0 = (blockIdx.x - EB_BLOCKS) * 32;
    for (int i = tid; i < 4096; i += 256) u.enc.w2[i] = w2[i];
    for (int i = tid; i < 224; i += 256) {
        int src = node0 * 7 + i;
        u.enc.xx[i / 7][i % 7] = (src < N_NODES * 7) ? x[src] : 0.f;
    }
    for (int i = tid; i < 512; i += 256) {
        int g = i >> 6, k = i & 63;
        int h = g & 3;
        u.enc.wf[g * 65 + k] = (g < 4) ? wsf[h * 64 + k] : wdf[h * 64 + k];
    }
    int c = tid & 63;
    int mg = tid >> 6;
    float w1c[7];
    #pragma unroll
    for (int k = 0; k < 7; ++k) w1c[k] = w1[k * 64 + c];
    float b1c = b1[c];
    __syncthreads();
    #pragma unroll
    for (int m = 0; m < 8; ++m) {
        int nn = mg * 8 + m;
        float a = b1c;
        #pragma unroll
        for (int k = 0; k < 7; ++k) a += u.enc.xx[nn][k] * w1c[k];
        u.enc.t[nn][c] = fmaxf(a, 0.f);
    }
    __syncthreads();
    float acc[8];
    float b2c = b2[c];
    #pragma unroll
    for (int m = 0; m < 8; ++m) acc[m] = b2c;
    #pragma unroll 4
    for (int k = 0; k < 64; ++k) {
        float w = u.enc.w2[k * 64 + c];
        #pragma unroll
        for (int m = 0; m < 8; ++m) acc[m] += u.enc.t[mg * 8 + m][k] * w;
    }
    #pragma unroll
    for (int m = 0; m < 8; ++m) {
        int nn = mg * 8 + m;
        int node = node0 + nn;
        u.enc.he[nn][c] = acc[m];
        if (node < N_NODES) henc[node * 64 + c] = f2bf(acc[m]);
    }
    __syncthreads();
    {
        int nn = tid >> 3, r = tid & 7;
        int node = node0 + nn;
        const float* wf = u.enc.wf + r * 65;
        float sum = 0.f;
        #pragma unroll 8
        for (int k = 0; k < 64; ++k) sum += u.enc.he[nn][k] * wf[k];
        if (node < N_NODES) {
            int hh = r & 3;
            if (r < 4) as1[node * 4 + hh] = sum;
            else       ad1[node * 4 + hh] = sum;
        }
    }
}

// ---------------- per-bucket CSR finalize: 1 block = 256-node bucket ----------------
__global__ __launch_bounds__(256) void bucket_csr_kernel(
    const int* __restrict__ ebuf, const int* __restrict__ bcur,
    int* __restrict__ rowbeg, int* __restrict__ degarr, int* __restrict__ csr_src) {
    __shared__ int s_deg[256];
    __shared__ int s_cur[256];
    __shared__ int s_w[4];
    int b = blockIdx.x;
    int tid = threadIdx.x;
    s_deg[tid] = 0;
    int cnt = bcur[b];
    int base = b * BCAP;
    const int* eb = ebuf + base;
    int node0 = b << BSHIFT;
    __syncthreads();
    for (int i = tid; i < cnt; i += 256) atomicAdd(&s_deg[eb[i] >> 16], 1);
    __syncthreads();
    int v = s_deg[tid];
    int lane = tid & 63, w = tid >> 6;
    int xv = v;
    #pragma unroll
    for (int off = 1; off < 64; off <<= 1) {
        int t = __shfl_up(xv, off);
        if (lane >= off) xv += t;
    }
    if (lane == 63) s_w[w] = xv;
    __syncthreads();
    if (tid == 0) {
        int a = 0;
        #pragma unroll
        for (int j = 0; j < 4; ++j) { int t = s_w[j]; s_w[j] = a; a += t; }
    }
    __syncthreads();
    int excl = xv - v + s_w[w];
    s_cur[tid] = excl;
    int node = node0 + tid;
    if (node < N_NODES) {
        rowbeg[node] = base + excl;
        degarr[node] = v;
    }
    __syncthreads();
    for (int i = tid; i < cnt; i += 256) {
        int p = eb[i];
        int pos = atomicAdd(&s_cur[p >> 16], 1);
        csr_src[base + pos] = p & 0xFFFF;
    }
}

// ---------------- GAT1 aggregate: 1 node per 8-lane group, 16B feature loads ----------------
__global__ __launch_bounds__(256) void aggregate1_kernel(
    const int* __restrict__ rowbeg, const int* __restrict__ degarr, const int* __restrict__ csr_src,
    const float* __restrict__ as, const float* __restrict__ ad,
    const unsigned short* __restrict__ henc, unsigned short* __restrict__ agg) {
    __shared__ int    ls[32][9];
    __shared__ float4 lp[32][9];
    int tid = threadIdx.x;
    int gg = tid >> 3, lane8 = tid & 7;
    int n = blockIdx.x * 32 + gg;
    if (n >= N_NODES) return;
    int base = rowbeg[n];
    int deg  = degarr[n];
    float4 add = *(const float4*)(ad + n * 4);

    float4 l = make_float4(0.f, 0.f, 0.f, 0.f);
    float acc[8][4];   // [feat][head], feats lane8*8..+7
    #pragma unroll
    for (int f = 0; f < 8; ++f)
        #pragma unroll
        for (int h = 0; h < 4; ++h) acc[f][h] = 0.f;

    for (int c0 = 0; c0 < deg; c0 += 8) {
        int j = c0 + lane8;
        int s = 0;
        float4 p = make_float4(0.f, 0.f, 0.f, 0.f);
        if (j < deg) {
            s = csr_src[base + j];
            float4 a = *(const float4*)(as + s * 4);
            p.x = __expf(lrelu(a.x + add.x));
            p.y = __expf(lrelu(a.y + add.y));
            p.z = __expf(lrelu(a.z + add.z));
            p.w = __expf(lrelu(a.w + add.w));
            l.x += p.x; l.y += p.y; l.z += p.z; l.w += p.w;
        }
        ls[gg][lane8] = s;
        lp[gg][lane8] = p;
        int cnt = min(8, deg - c0);
        const int*    lsw = ls[gg];
        const float4* lpw = lp[gg];
        int e = 0;
        for (; e + 4 <= cnt; e += 4) {
            bf16x8 r0 = *(const bf16x8*)(henc + lsw[e+0] * 64 + lane8 * 8);
            bf16x8 r1 = *(const bf16x8*)(henc + lsw[e+1] * 64 + lane8 * 8);
            bf16x8 r2 = *(const bf16x8*)(henc + lsw[e+2] * 64 + lane8 * 8);
            bf16x8 r3 = *(const bf16x8*)(henc + lsw[e+3] * 64 + lane8 * 8);
            float4 p0 = lpw[e+0], p1 = lpw[e+1], p2 = lpw[e+2], p3 = lpw[e+3];
            acc8(r0, p0, acc); acc8(r1, p1, acc);
            acc8(r2, p2, acc); acc8(r3, p3, acc);
        }
        for (; e < cnt; ++e) {
            bf16x8 r = *(const bf16x8*)(henc + lsw[e] * 64 + lane8 * 8);
            acc8(r, lpw[e], acc);
        }
    }
    // denominator reduce across the 8-lane group
    #pragma unroll
    for (int off = 1; off < 8; off <<= 1) {
        l.x += __shfl_xor(l.x, off);
        l.y += __shfl_xor(l.y, off);
        l.z += __shfl_xor(l.z, off);
        l.w += __shfl_xor(l.w, off);
    }
    float inv[4];
    inv[0] = 1.f / (l.x + 1e-16f);
    inv[1] = 1.f / (l.y + 1e-16f);
    inv[2] = 1.f / (l.z + 1e-16f);
    inv[3] = 1.f / (l.w + 1e-16f);
    const size_t PL = (size_t)N_NODES * 64;
    #pragma unroll
    for (int h = 0; h < 4; ++h) {
        bf16x8 o;
        #pragma unroll
        for (int f = 0; f < 8; ++f) o[f] = (short)f2bf(acc[f][h] * inv[h]);
        *(bf16x8*)(agg + h * PL + (size_t)n * 64 + lane8 * 8) = o;
    }
}

// ---------------- fused GEMM1+GEMM2 (MFMA): 64 nodes/block, 8 waves, hi-only weights ----------------
// bf16-hi weights only (inputs already bf16-rounded; lo-correction below input noise).
// LDS 72KB -> 2 blocks/CU. phase A: wave w -> rows [(w&3)*16,+16), heads {2*(w>>2),+1}
// phase C: rows same, cols [(w>>2)*32,+32); gc on waves w<4. Row-XOR swizzle byte ^= (row&7)<<4.
__global__ __launch_bounds__(512, 1) void gemm12_kernel(
    const unsigned short* __restrict__ agg, const unsigned short* __restrict__ wtb,
    const float* __restrict__ g1b, unsigned short* __restrict__ h2,
    float* __restrict__ as2, float* __restrict__ ad2) {
    __shared__ unsigned short sw[20480];   // 40KB: phase A = W1 hi; phase C = W2 hi + gc hi
    __shared__ unsigned short s1[16384];   // 32KB out1 tile [64][256], row-xor swizzled
    int tid = threadIdx.x;
    int node0 = blockIdx.x * 64;
    int lane = tid & 63, w = tid >> 6;
    int lrow = lane & 15, g = lane >> 4;
    int rw = w & 3, hp = w >> 2;           // row-tile / head-pair (phase A) = col-half (phase C)
    const size_t PL = (size_t)N_NODES * 64;

    // stage W1 hi (32KB, 2048 uint4): row stride 128B = 8 uint4 -> xor (i>>3)&7
    {
        const uint4* src = (const uint4*)(wtb + W1HI);
        uint4* dst = (uint4*)sw;
        #pragma unroll
        for (int r = 0; r < 4; ++r) {
            int i = r * 512 + tid;
            dst[i ^ ((i >> 3) & 7)] = src[i];
        }
    }
    // A-fragments + biases (latency hides under staging)
    int arow = node0 + rw * 16 + lrow;
    if (arow >= N_NODES) arow = N_NODES - 1;   // clamp; garbage rows masked at final store
    bf16x8 aF[2][2];
    #pragma unroll
    for (int hh = 0; hh < 2; ++hh)
        #pragma unroll
        for (int ks = 0; ks < 2; ++ks)
            aF[hh][ks] = *(const bf16x8*)(agg + (size_t)(hp * 2 + hh) * PL + (size_t)arow * 64 + ks * 32 + g * 8);
    float bb[2][4];
    #pragma unroll
    for (int hh = 0; hh < 2; ++hh)
        #pragma unroll
        for (int qt = 0; qt < 4; ++qt)
            bb[hh][qt] = g1b[(hp * 2 + hh) * 64 + qt * 16 + lrow];
    __syncthreads();

    // ---- phase A: gemm1, 2 heads, rows [rw*16,+16) ----
    f32x4 acc1[2][4];
    #pragma unroll
    for (int hh = 0; hh < 2; ++hh)
        #pragma unroll
        for (int qt = 0; qt < 4; ++qt) acc1[hh][qt] = (f32x4){0.f, 0.f, 0.f, 0.f};
    #pragma unroll
    for (int hh = 0; hh < 2; ++hh) {
        int h = hp * 2 + hh;
        #pragma unroll
        for (int ks = 0; ks < 2; ++ks) {
            #pragma unroll
            for (int qt = 0; qt < 4; ++qt) {
                int q = qt * 16 + lrow;
                int byt = (h * 8192 + q * 128 + ks * 64 + g * 16) ^ ((q & 7) << 4);
                bf16x8 bH = *(const bf16x8*)((char*)sw + byt);
                acc1[hh][qt] = MFMA16(aF[hh][ks], bH, acc1[hh][qt]);
            }
        }
    }
    // epilogue A: bias + ELU -> s1 (swizzled). D layout: col = lrow, row = g*4+i.
    #pragma unroll
    for (int hh = 0; hh < 2; ++hh) {
        int h = hp * 2 + hh;
        #pragma unroll
        for (int qt = 0; qt < 4; ++qt) {
            int col = h * 64 + qt * 16 + lrow;
            #pragma unroll
            for (int i = 0; i < 4; ++i) {
                int r = rw * 16 + g * 4 + i;
                float t = acc1[hh][qt][i] + bb[hh][qt];
                t = t > 0.f ? t : (__expf(t) - 1.f);
                int byt = (r * 512 + col * 2) ^ ((r & 7) << 4);
                *(unsigned short*)((char*)s1 + byt) = f2bf(t);
            }
        }
    }
    __syncthreads();
    // stage W2 hi (32KB, 2048 uint4) + gc hi (8KB, 512 uint4) global->LDS:
    // row stride 512B = 32 uint4 -> xor (i>>5)&7 within each region
    {
        const uint4* srcw = (const uint4*)(wtb + W2HI);
        const uint4* srcg = (const uint4*)(wtb + GCHI);
        uint4* dst = (uint4*)sw;
        #pragma unroll
        for (int r = 0; r < 4; ++r) {
            int i = r * 512 + tid;
            dst[i ^ ((i >> 5) & 7)] = srcw[i];
        }
        {
            int i = tid;   // 0..511
            uint4* dst2 = dst + 2048;
            dst2[i ^ ((i >> 5) & 7)] = srcg[i];
        }
    }
    __syncthreads();
    // ---- phase C: gemm2 + gc, K=256 from s1; cols [hp*32,+32) ----
    f32x4 acc2[2];
    f32x4 accg = (f32x4){0.f, 0.f, 0.f, 0.f};
    acc2[0] = (f32x4){0.f, 0.f, 0.f, 0.f};
    acc2[1] = (f32x4){0.f, 0.f, 0.f, 0.f};
    int rloc = rw * 16 + lrow;
    int rx = (rloc & 7) << 4;
    #pragma unroll
    for (int ks = 0; ks < 8; ++ks) {
        int kb = ks * 64 + g * 16;
        bf16x8 aF2 = *(const bf16x8*)((char*)s1 + ((rloc * 512 + kb) ^ rx));
        #pragma unroll
        for (int qt = 0; qt < 2; ++qt) {
            int c = (hp * 2 + qt) * 16 + lrow;
            int byt = (c * 512 + kb) ^ ((c & 7) << 4);
            bf16x8 bH = *(const bf16x8*)((char*)sw + byt);
            acc2[qt] = MFMA16(aF2, bH, acc2[qt]);
        }
        if (hp == 0) {
            int byt = 32768 + ((lrow * 512 + kb) ^ ((lrow & 7) << 4));
            bf16x8 gH = *(const bf16x8*)((char*)sw + byt);
            accg = MFMA16(aF2, gH, accg);
        }
    }
    // epilogue C: h2 bf16 store + as2/ad2 (gc cols: even->as, odd->ad)
    #pragma unroll
    for (int i = 0; i < 4; ++i) {
        int node = node0 + rw * 16 + g * 4 + i;
        if (node < N_NODES) {
            #pragma unroll
            for (int qt = 0; qt < 2; ++qt)
                h2[(size_t)node * 64 + (hp * 2 + qt) * 16 + lrow] = f2bf(acc2[qt][i]);
            if (hp == 0 && lrow < 8) {
                float v = accg[i];
                int hh = lrow >> 1;
                if (lrow & 1) ad2[node * 4 + hh] = v;
                else          as2[node * 4 + hh] = v;
            }
        }
    }
}

// ---------------- GAT2 aggregate + fused decoder: 1 node per 16-lane group ----------------
// weight staging = 4 float4/thread (full 16KB w1) + w2; one barrier; decode is
// intra-16-lane-group (v in group-local LDS row, wave-synchronous, no block barrier)
__global__ __launch_bounds__(256) void aggdec2_kernel(
    const int* __restrict__ rowbeg, const int* __restrict__ degarr, const int* __restrict__ csr_src,
    const float* __restrict__ as, const float* __restrict__ ad,
    const unsigned short* __restrict__ h, const float* __restrict__ gb,
    const float* __restrict__ w1, const float* __restrict__ b1,
    const float* __restrict__ w2, const float* __restrict__ b2,
    float* __restrict__ out) {
    __shared__ int    ls[16][17];
    __shared__ float4 lp[16][17];
    __shared__ float  s_w1[4096];    // dec_w1 [k][c], 16KB
    __shared__ float  s_w2[256];     // dec_w2 [c][j], 1KB
    __shared__ float  s_v[16][68];   // per-group decoder input row
    int tid = threadIdx.x;
    // stage decoder weights: 4096 floats = 1024 float4 = 4 float4/thread (+64 threads for w2)
    #pragma unroll
    for (int r = 0; r < 4; ++r) {
        int i = r * 256 + tid;       // 0..1023 float4 index
        *(float4*)(s_w1 + i * 4) = *(const float4*)(w1 + i * 4);
    }
    if (tid < 64) *(float4*)(s_w2 + tid * 4) = *(const float4*)(w2 + tid * 4);
    __syncthreads();

    int gg = tid >> 4, lane16 = tid & 15;
    int n = blockIdx.x * 16 + gg;    // N_NODES = 3125*16 exactly -> always < N_NODES
    if (n >= N_NODES) return;
    int base = rowbeg[n];
    int deg  = degarr[n];
    int head = lane16 >> 2;          // 4 feats per lane, all in this head
    float4 add = *(const float4*)(ad + n * 4);

    float4 l = make_float4(0.f, 0.f, 0.f, 0.f);
    float acc[4];
    acc[0] = acc[1] = acc[2] = acc[3] = 0.f;

    for (int c0 = 0; c0 < deg; c0 += 16) {
        int j = c0 + lane16;
        int s = 0;
        float4 p = make_float4(0.f, 0.f, 0.f, 0.f);
        if (j < deg) {
            s = csr_src[base + j];
            float4 a = *(const float4*)(as + s * 4);
            p.x = __expf(lrelu(a.x + add.x));
            p.y = __expf(lrelu(a.y + add.y));
            p.z = __expf(lrelu(a.z + add.z));
            p.w = __expf(lrelu(a.w + add.w));
            l.x += p.x; l.y += p.y; l.z += p.z; l.w += p.w;
        }
        ls[gg][lane16] = s;
        lp[gg][lane16] = p;
        int cnt = min(16, deg - c0);
        const int*   lsw = ls[gg];
        const float* lpf = (const float*)lp[gg];
        int e = 0;
        for (; e + 4 <= cnt; e += 4) {
            ushort4 r0 = *(const ushort4*)(h + lsw[e+0] * 64 + lane16 * 4);
            ushort4 r1 = *(const ushort4*)(h + lsw[e+1] * 64 + lane16 * 4);
            ushort4 r2 = *(const ushort4*)(h + lsw[e+2] * 64 + lane16 * 4);
            ushort4 r3 = *(const ushort4*)(h + lsw[e+3] * 64 + lane16 * 4);
            float p0 = lpf[(e+0) * 4 + head];
            float p1 = lpf[(e+1) * 4 + head];
            float p2 = lpf[(e+2) * 4 + head];
            float p3 = lpf[(e+3) * 4 + head];
            acc[0] += bf2f(r0.x)*p0 + bf2f(r1.x)*p1 + bf2f(r2.x)*p2 + bf2f(r3.x)*p3;
            acc[1] += bf2f(r0.y)*p0 + bf2f(r1.y)*p1 + bf2f(r2.y)*p2 + bf2f(r3.y)*p3;
            acc[2] += bf2f(r0.z)*p0 + bf2f(r1.z)*p1 + bf2f(r2.z)*p2 + bf2f(r3.z)*p3;
            acc[3] += bf2f(r0.w)*p0 + bf2f(r1.w)*p1 + bf2f(r2.w)*p2 + bf2f(r3.w)*p3;
        }
        for (; e < cnt; ++e) {
            ushort4 r = *(const ushort4*)(h + lsw[e] * 64 + lane16 * 4);
            float pe = lpf[e * 4 + head];
            acc[0] += bf2f(r.x) * pe;
            acc[1] += bf2f(r.y) * pe;
            acc[2] += bf2f(r.z) * pe;
            acc[3] += bf2f(r.w) * pe;
        }
    }
    #pragma unroll
    for (int off = 1; off < 16; off <<= 1) {
        l.x += __shfl_xor(l.x, off);
        l.y += __shfl_xor(l.y, off);
        l.z += __shfl_xor(l.z, off);
        l.w += __shfl_xor(l.w, off);
    }
    float lh = (head == 0) ? l.x : (head == 1) ? l.y : (head == 2) ? l.z : l.w;
    float inv = 1.f / (lh + 1e-16f);
    // ---- fused decoder (intra-group; wave-synchronous LDS, no block barrier) ----
    int c0v = lane16 * 4;
    float4 vv;
    vv.x = acc[0] * inv + gb[c0v + 0];
    vv.y = acc[1] * inv + gb[c0v + 1];
    vv.z = acc[2] * inv + gb[c0v + 2];
    vv.w = acc[3] * inv + gb[c0v + 3];
    *(float4*)(&s_v[gg][c0v]) = vv;
    // layer 1: t[c] = relu(b1[c] + sum_k v[k]*w1[k][c]), c = c0v..c0v+3
    float t0 = b1[c0v + 0], t1 = b1[c0v + 1], t2 = b1[c0v + 2], t3 = b1[c0v + 3];
    #pragma unroll 8
    for (int k = 0; k < 64; ++k) {
        float vk = s_v[gg][k];
        float4 wv = *(const float4*)(s_w1 + k * 64 + c0v);
        t0 += vk * wv.x; t1 += vk * wv.y; t2 += vk * wv.z; t3 += vk * wv.w;
    }
    t0 = fmaxf(t0, 0.f); t1 = fmaxf(t1, 0.f); t2 = fmaxf(t2, 0.f); t3 = fmaxf(t3, 0.f);
    // layer 2: out[j] = b2[j] + sum_c t[c]*w2[c][j] (per-lane partial, 16-lane tree reduce)
    float4 w20 = *(const float4*)(s_w2 + (c0v + 0) * 4);
    float4 w21 = *(const float4*)(s_w2 + (c0v + 1) * 4);
    float4 w22 = *(const float4*)(s_w2 + (c0v + 2) * 4);
    float4 w23 = *(const float4*)(s_w2 + (c0v + 3) * 4);
    float o0 = t0 * w20.x + t1 * w21.x + t2 * w22.x + t3 * w23.x;
    float o1 = t0 * w20.y + t1 * w21.y + t2 * w22.y + t3 * w23.y;
    float o2 = t0 * w20.z + t1 * w21.z + t2 * w22.z + t3 * w23.z;
    float o3 = t0 * w20.w + t1 * w21.w + t2 * w22.w + t3 * w23.w;
    #pragma unroll
    for (int off = 1; off < 16; off <<= 1) {
        o0 += __shfl_xor(o0, off);
        o1 += __shfl_xor(o1, off);
        o2 += __shfl_xor(o2, off);
        o3 += __shfl_xor(o3, off);
    }
    if (lane16 == 0) {
        *(float4*)(out + (size_t)n * 4) =
            make_float4(o0 + b2[0], o1 + b2[1], o2 + b2[2], o3 + b2[3]);
    }
}

extern "C" void kernel_launch(void* const* d_in, const int* in_sizes, int n_in,
                              void* d_out, int out_size, void* d_ws, size_t ws_size,
                              hipStream_t stream) {
    const float* x      = (const float*)d_in[0];
    const int*   ei     = (const int*)d_in[1];
    const float* enc_w1 = (const float*)d_in[2];
    const float* enc_b1 = (const float*)d_in[3];
    const float* enc_w2 = (const float*)d_in[4];
    const float* enc_b2 = (const float*)d_in[5];
    const float* g1_w   = (const float*)d_in[6];
    const float* g1_as  = (const float*)d_in[7];
    const float* g1_ad  = (const float*)d_in[8];
    const float* g1_b   = (const float*)d_in[9];
    const float* g2_w   = (const float*)d_in[10];
    const float* g2_as  = (const float*)d_in[11];
    const float* g2_ad  = (const float*)d_in[12];
    const float* g2_b   = (const float*)d_in[13];
    const float* dec_w1 = (const float*)d_in[14];
    const float* dec_b1 = (const float*)d_in[15];
    const float* dec_w2 = (const float*)d_in[16];
    const float* dec_b2 = (const float*)d_in[17];

    const int N = N_NODES;

    // workspace layout (float offsets)
    float* ws   = (float*)d_ws;
    unsigned short* henc = (unsigned short*)ws;                   // 3.2M bf16 = [0,1.6M) floats
    unsigned short* wtb  = (unsigned short*)(ws + 1700000);       // 73728 bf16 weight table (dead gap)
    unsigned short* agg  = (unsigned short*)(ws + 3200000);       // 12.8M bf16 planar [h][n][k]
    unsigned short* h2   = (unsigned short*)(ws + 16000000);      // 3.2M bf16
    unsigned short* out1 = (unsigned short*)(ws + 22400000);      // (dead; ebuf alias only)
    float* as1  = ws + 35200000;
    float* ad1  = as1 + 200000;
    float* as2  = ad1 + 200000;
    float* ad2  = as2 + 200000;
    float* wsf  = ad2 + 200000;              // 256
    float* wdf  = wsf + 256;                 // 256
    int*   ebuf = (int*)out1;                // NBUK*BCAP ints = 4.8 MB
    int*   ib      = (int*)(ws + 36001024);
    int*   bcur    = ib;                     // 256
    int*   rowbeg  = ib + 256;               // 50,176
    int*   degarr  = ib + 50432;             // 50,176
    int*   csr_src = ib + 100608;            // NBUK*BCAP = 1,204,224

    // 1. zero bucket cursors + fold attention vectors + MFMA weight prep
    zerofold_kernel<<<20, 256, 0, stream>>>(bcur, g1_w, g1_as, g1_ad, wsf, wdf,
                                            g2_w, g2_as, g2_ad, wtb);
    // 2. bucket-scatter edges (packed int) + encoder/alpha1 (fused; henc bf16)
    mega_kernel<<<EB_BLOCKS + ENC_BLOCKS, 256, 0, stream>>>(
        ei, bcur, ebuf, x, enc_w1, enc_b1, enc_w2, enc_b2, wsf, wdf, henc, as1, ad1);
    // 3. per-bucket CSR finalize
    bucket_csr_kernel<<<NBUK, 256, 0, stream>>>(ebuf, bcur, rowbeg, degarr, csr_src);

    // 4. GAT1 aggregate (8-lane groups, 16B loads, bf16 planar out)
    aggregate1_kernel<<<NAGG8_BLOCKS, 256, 0, stream>>>(rowbeg, degarr, csr_src, as1, ad1, henc, agg);
    // 5. fused GEMM1+GEMM2 (MFMA, 8 waves, hi-only LDS weights, 2 blocks/CU)
    gemm12_kernel<<<G12NB, 512, 0, stream>>>(agg, wtb, g1_b, h2, as2, ad2);

    // 6. GAT2 aggregate + fused decoder (16-lane groups; writes d_out directly)
    aggdec2_kernel<<<NAGG_BLOCKS, 256, 0, stream>>>(rowbeg, degarr, csr_src, as2, ad2, h2,
                                                    g2_b, dec_w1, dec_b1, dec_w2, dec_b2,
                                                    (float*)d_out);
}